// Round 10
// baseline (267.930 us; speedup 1.0000x reference)
//
#include <hip/hip_runtime.h>
#include <hip/hip_bf16.h>
#include <stdint.h>

// B=16,T=512,H=1024 -> N=M=8192 rows, H=1024.
// out[0] = mean_i [ log(sum_j exp(sim_ij/T)) - max_j sim_ij / T ]
// out[1] = 1 - mean_i dot(Tn[pos[i]], Tn[pos[i+1]])
// sim computed in fp8 e4m3 (MFMA 16x16x32_fp8_fp8, fp32 accumulate).
//
// fp8 tiled layout: row r, k -> group g=r>>4, byte off = g*16384
//   + (k>>5)*512 + ((k&31)>>3)*128 + (r&15)*8 + (k&7)
// -> global_load_lds(1KB) is a contiguous copy; ds_read_b64 at
//    (chunk*512 + lane*8) is exactly the 16x16x32 A/B fragment.
// T also kept row-major fp8 (Tr) for the ctx pass.

#define HDIM 1024
#define NROW 8192
#define TEMP_INV (1.0f / 0.07f)

typedef __attribute__((ext_vector_type(4))) float float4v;  // MFMA C/D
typedef __attribute__((ext_vector_type(2))) float float2v;

// ws layout (bytes)
#define SN_OFF   ((size_t)0)                        // 8 MB fp8 tiled S
#define TN_OFF   ((size_t)8388608)                  // 8 MB fp8 tiled T
#define TR_OFF   ((size_t)16777216)                 // 8 MB fp8 row-major T
#define SUM_OFF  ((size_t)25165824)                 // 8192 float sum-exp
#define PMX_OFF  (SUM_OFF + 32768)                  // 8192 u64 packed (max,~idx)
#define ACC_OFF  (PMX_OFF + 65536)                  // 2 floats
#define CNT_OFF  (ACC_OFF + 64)                     // 1 uint

// async 16B global -> LDS (per-lane gptr; lane i lands at lds_base + i*16)
static __device__ __forceinline__ void gload_lds16(const void* gptr, void* lptr) {
    __builtin_amdgcn_global_load_lds(
        (const __attribute__((address_space(1))) void*)gptr,
        (__attribute__((address_space(3))) void*)(uintptr_t)(uint32_t)(uintptr_t)lptr,
        16, 0, 0);
}

// dot of 4 fp8 pairs packed in two dwords
static __device__ __forceinline__ float fp8dot4(unsigned a, unsigned b) {
    float2v al = __builtin_amdgcn_cvt_pk_f32_fp8((int)a, false);
    float2v ah = __builtin_amdgcn_cvt_pk_f32_fp8((int)a, true);
    float2v bl = __builtin_amdgcn_cvt_pk_f32_fp8((int)b, false);
    float2v bh = __builtin_amdgcn_cvt_pk_f32_fp8((int)b, true);
    return al[0]*bl[0] + al[1]*bl[1] + ah[0]*bh[0] + ah[1]*bh[1];
}

// ---------------- Phase 0: normalize -> fp8, fully coalesced -------------------
__global__ __launch_bounds__(256)
void norm_kernel(const float* __restrict__ hs, const float* __restrict__ ht,
                 char* __restrict__ Sn, char* __restrict__ Tn, char* __restrict__ Tr,
                 float* __restrict__ sumexp, unsigned long long* __restrict__ pmax,
                 float* __restrict__ acc, unsigned* __restrict__ cnt) {
    const int b = blockIdx.x;                       // 0..1023
    const int t = threadIdx.x;
    const int wave = t >> 6, lane = t & 63;
    const bool isT = (b >= 512);
    const int g = isT ? (b - 512) : b;
    const float* in = (isT ? ht : hs) + (size_t)g * 16 * HDIM;
    char* outTiled = (isT ? Tn : Sn) + (size_t)g * 16384;

    __shared__ float sq[16][256];                   // 16 KB, reused as tiled buf
    __shared__ float sscale[16];

    float4v v[16];
    #pragma unroll
    for (int i = 0; i < 16; ++i) {
        v[i] = ((const float4v*)in)[i * 256 + t];
        sq[i][t] = v[i][0]*v[i][0] + v[i][1]*v[i][1] + v[i][2]*v[i][2] + v[i][3]*v[i][3];
    }
    __syncthreads();
    #pragma unroll
    for (int j = 0; j < 4; ++j) {
        const int ri = wave * 4 + j;
        float s = sq[ri][lane] + sq[ri][lane + 64] + sq[ri][lane + 128] + sq[ri][lane + 192];
        #pragma unroll
        for (int off = 1; off < 64; off <<= 1) s += __shfl_xor(s, off);
        if (lane == 0) sscale[ri] = 1.0f / fmaxf(sqrtf(s), 1e-12f);
    }
    __syncthreads();                                // scales ready; sq reads done

    char* tiled = (char*)sq;
    const int koff = (t >> 3) * 512 + ((t >> 1) & 3) * 128 + (t & 1) * 4;  // k0 = 4t
    #pragma unroll
    for (int i = 0; i < 16; ++i) {
        const float sc = sscale[i];
        int d = __builtin_amdgcn_cvt_pk_fp8_f32(v[i][0]*sc, v[i][1]*sc, 0, false);
        d     = __builtin_amdgcn_cvt_pk_fp8_f32(v[i][2]*sc, v[i][3]*sc, d, true);
        *(int*)(tiled + koff + i * 8) = d;
        if (isT) ((int*)(Tr + (size_t)(g * 16 + i) * HDIM))[t] = d;   // coalesced
    }
    __syncthreads();
    #pragma unroll
    for (int j = 0; j < 4; ++j)
        ((uint4*)outTiled)[j * 256 + t] = ((const uint4*)tiled)[j * 256 + t];

    if (!isT && t < 16) { sumexp[b * 16 + t] = 0.f; pmax[b * 16 + t] = 0ull; }
    if (b == 0 && t == 16) { acc[0] = 0.f; acc[1] = 0.f; *cnt = 0u; }
}

// ---------------- Phase 1: pipelined multi-strip MFMA flash pass ---------------
// Grid 1024 = 32 row-tiles x 32 col-tiles. Block = 512 thr = 8 waves (4x2),
// tile 256 rows x 256 cols as 2 strips of 128, wave tile 64x64.
// K-loop is software-pipelined with double-buffered LDS: the barrier at iter kb
// drains loads issued at iter kb-1 (one full compute phase in flight), so the
// vmcnt(0) drain that was the ~75% per-iter stall overlaps MFMA compute.
// Cross-strip prefetch at kb=15 hides the strip boundary too.
__global__ __launch_bounds__(512, 4)
void flash_kernel(const char* __restrict__ Sn, const char* __restrict__ Tn,
                  float* __restrict__ sumexp, unsigned long long* __restrict__ pmax) {
    __shared__ __align__(16) char As[2][16384];     // dbuf: 16 groups x 1KB
    __shared__ __align__(16) char Bs[2][8192];      // dbuf: 8 groups x 1KB
    __shared__ float pbSe[256];
    __shared__ unsigned long long pbPk[256];
    __shared__ float stSe[256];
    __shared__ unsigned long long stPk[256];
    const int t = threadIdx.x;
    const int wave = t >> 6, lane = t & 63;
    const int quad = lane >> 4, l16 = lane & 15;
    const int rbase  = (int)(blockIdx.x & 31) * 256;
    const int cbase0 = (int)(blockIdx.x >> 5) * 256;

    if (t < 256) { stSe[t] = 0.f; stPk[t] = 0ull; }

    const int wm = (wave & 3) * 64, wn = (wave >> 2) * 64;
    const char* ga0 = Sn + (size_t)(rbase / 16 + wave * 2 + 0) * 16384 + lane * 16;
    const char* ga1 = Sn + (size_t)(rbase / 16 + wave * 2 + 1) * 16384 + lane * 16;
    const char* gbs[2];
    gbs[0] = Tn + (size_t)((cbase0 +   0) / 16 + wave) * 16384 + lane * 16;
    gbs[1] = Tn + (size_t)((cbase0 + 128) / 16 + wave) * 16384 + lane * 16;

    // prologue: strip 0, kb 0 -> buffer 0
    gload_lds16(ga0,    &As[0][(wave * 2 + 0) * 1024]);
    gload_lds16(ga1,    &As[0][(wave * 2 + 1) * 1024]);
    gload_lds16(gbs[0], &Bs[0][wave * 1024]);

    for (int s = 0; s < 2; ++s) {
        const int cbase = cbase0 + s * 128;

        float4v acc[4][4];
        #pragma unroll
        for (int i = 0; i < 4; ++i)
            #pragma unroll
            for (int j = 0; j < 4; ++j) acc[i][j] = (float4v){0.f, 0.f, 0.f, 0.f};

        for (int kb = 0; kb < 16; ++kb) {
            const int p = kb & 1;
            __syncthreads();                        // buf[p] (issued last iter) landed
            if (kb < 15) {                          // prefetch kb+1 into buf[1-p]
                gload_lds16(ga0 + (kb + 1) * 1024,    &As[1 - p][(wave * 2 + 0) * 1024]);
                gload_lds16(ga1 + (kb + 1) * 1024,    &As[1 - p][(wave * 2 + 1) * 1024]);
                gload_lds16(gbs[s] + (kb + 1) * 1024, &Bs[1 - p][wave * 1024]);
            } else if (s == 0) {                    // cross-strip prefetch (buf 0 free)
                gload_lds16(ga0,    &As[0][(wave * 2 + 0) * 1024]);
                gload_lds16(ga1,    &As[0][(wave * 2 + 1) * 1024]);
                gload_lds16(gbs[1], &Bs[0][wave * 1024]);
            }
            #pragma unroll
            for (int ks = 0; ks < 2; ++ks) {
                long af[4], bf[4];
                #pragma unroll
                for (int i = 0; i < 4; ++i)
                    af[i] = *(const long*)(&As[p][((wave & 3) * 4 + i) * 1024 + ks * 512 + lane * 8]);
                #pragma unroll
                for (int j = 0; j < 4; ++j)
                    bf[j] = *(const long*)(&Bs[p][((wave >> 2) * 4 + j) * 1024 + ks * 512 + lane * 8]);
                #pragma unroll
                for (int i = 0; i < 4; ++i)
                    #pragma unroll
                    for (int j = 0; j < 4; ++j)
                        acc[i][j] = __builtin_amdgcn_mfma_f32_16x16x32_fp8_fp8(af[i], bf[j], acc[i][j], 0, 0, 0);
            }
        }

        // strip epilogue: lane holds sim[rbase+wm+i*16+quad*4+r][cbase+wn+j*16+l16]
        float se_v[4][4]; unsigned long long pk_v[4][4];
        #pragma unroll
        for (int i = 0; i < 4; ++i) {
            #pragma unroll
            for (int r = 0; r < 4; ++r) {
                float se = 0.f; float mx = -2.f; int mi = 0x7fffffff;
                #pragma unroll
                for (int j = 0; j < 4; ++j) {
                    float v = acc[i][j][r];
                    se += __expf(v * TEMP_INV);
                    int col = cbase + wn + j * 16 + l16;
                    if (v > mx || (v == mx && col < mi)) { mx = v; mi = col; }
                }
                #pragma unroll
                for (int off = 1; off < 16; off <<= 1) {
                    se += __shfl_xor(se, off);
                    float om = __shfl_xor(mx, off);
                    int oi = __shfl_xor(mi, off);
                    if (om > mx || (om == mx && oi < mi)) { mx = om; mi = oi; }
                }
                se_v[i][r] = se;
                pk_v[i][r] = ((unsigned long long)__float_as_uint(mx + 2.0f) << 32)
                             | (unsigned long long)(0xffffffffu - (unsigned)mi);
            }
        }
        if (wave < 4 && l16 == 0) {
            #pragma unroll
            for (int i = 0; i < 4; ++i)
                #pragma unroll
                for (int r = 0; r < 4; ++r) {
                    int rl = wm + i * 16 + quad * 4 + r;
                    pbSe[rl] = se_v[i][r]; pbPk[rl] = pk_v[i][r];
                }
        }
        __syncthreads();
        if (wave >= 4 && l16 == 0) {
            #pragma unroll
            for (int i = 0; i < 4; ++i)
                #pragma unroll
                for (int r = 0; r < 4; ++r) {
                    int rl = wm + i * 16 + quad * 4 + r;
                    float se = se_v[i][r] + pbSe[rl];
                    unsigned long long pk = pk_v[i][r];
                    unsigned long long po = pbPk[rl];
                    if (po > pk) pk = po;
                    stSe[rl] += se;
                    if (pk > stPk[rl]) stPk[rl] = pk;
                }
        }
        __syncthreads();
    }

    if (t < 256) {
        atomicAdd(&sumexp[rbase + t], stSe[t]);
        atomicMax(&pmax[rbase + t], stPk[t]);
    }
}

// ---------------- Phase 2: fused loss + ctx + finalize -------------------------
__global__ __launch_bounds__(256)
void tail_kernel(const float* __restrict__ sumexp,
                 const unsigned long long* __restrict__ pmax,
                 const char* __restrict__ Tr,
                 float* __restrict__ acc, unsigned* __restrict__ cnt,
                 float* __restrict__ out) {
    const int blk = blockIdx.x;                     // 0..255
    const int t = threadIdx.x, wave = t >> 6, lane = t & 63;

    if (wave == 0) {
        int r = blk * 32 + (lane & 31);
        unsigned long long p = pmax[r];
        float mx = __uint_as_float((unsigned)(p >> 32)) - 2.0f;
        float loss = logf(sumexp[r]) - mx * TEMP_INV;
        #pragma unroll
        for (int off = 1; off < 32; off <<= 1) loss += __shfl_xor(loss, off);
        if (lane == 0) atomicAdd(acc + 0, loss);    // lanes 0..31 summed once
    }

    float s = 0.f;
    #pragma unroll
    for (int it = 0; it < 8; ++it) {
        int g = blk * 32 + wave * 8 + it;
        if (g < NROW - 1) {
            unsigned long long pa = pmax[g], pb = pmax[g + 1];
            int ia = (int)(0xffffffffu - (unsigned)(pa & 0xffffffffu));
            int ib = (int)(0xffffffffu - (unsigned)(pb & 0xffffffffu));
            uint4 va = ((const uint4*)(Tr + (size_t)ia * HDIM))[lane];
            uint4 vb = ((const uint4*)(Tr + (size_t)ib * HDIM))[lane];
            s += fp8dot4(va.x, vb.x) + fp8dot4(va.y, vb.y)
               + fp8dot4(va.z, vb.z) + fp8dot4(va.w, vb.w);
        }
    }
    #pragma unroll
    for (int off = 1; off < 64; off <<= 1) s += __shfl_xor(s, off);
    __shared__ float red[4];
    if (lane == 0) red[wave] = s;
    __syncthreads();
    if (t == 0) atomicAdd(acc + 1, red[0] + red[1] + red[2] + red[3]);

    __threadfence();
    __shared__ unsigned done;
    if (t == 0) done = atomicAdd(cnt, 1u);
    __syncthreads();
    if (t == 0 && done == 255u) {
        float l0 = atomicAdd(acc + 0, 0.0f);        // device-scope RMW read
        float l1 = atomicAdd(acc + 1, 0.0f);
        out[0] = l0 / (float)NROW;
        out[1] = 1.0f - l1 / (float)(NROW - 1);
    }
}

extern "C" void kernel_launch(void* const* d_in, const int* in_sizes, int n_in,
                              void* d_out, int out_size, void* d_ws, size_t ws_size,
                              hipStream_t stream) {
    const float* hs = (const float*)d_in[0];
    const float* ht = (const float*)d_in[1];
    char* ws = (char*)d_ws;
    char* Sn = ws + SN_OFF;
    char* Tn = ws + TN_OFF;
    char* Tr = ws + TR_OFF;
    float* sumexp = (float*)(ws + SUM_OFF);
    unsigned long long* pmax = (unsigned long long*)(ws + PMX_OFF);
    float* acc = (float*)(ws + ACC_OFF);
    unsigned* cnt = (unsigned*)(ws + CNT_OFF);
    float* out = (float*)d_out;

    norm_kernel<<<1024, 256, 0, stream>>>(hs, ht, Sn, Tn, Tr, sumexp, pmax, acc, cnt);
    flash_kernel<<<1024, 512, 0, stream>>>(Sn, Tn, sumexp, pmax);
    tail_kernel<<<256, 256, 0, stream>>>(sumexp, pmax, Tr, acc, cnt, out);
}

// Round 11
// 252.801 us; speedup vs baseline: 1.0598x; 1.0598x over previous
//
#include <hip/hip_runtime.h>
#include <hip/hip_bf16.h>
#include <stdint.h>

// B=16,T=512,H=1024 -> N=M=8192 rows, H=1024.
// out[0] = mean_i [ log(sum_j exp(sim_ij/T)) - max_j sim_ij / T ]
// out[1] = 1 - mean_i dot(Tn[pos[i]], Tn[pos[i+1]])
// sim computed in fp8 e4m3 (MFMA 16x16x32_fp8_fp8, fp32 accumulate).
//
// fp8 tiled layout: row r, k -> group g=r>>4, byte off = g*16384
//   + (k>>5)*512 + ((k&31)>>3)*128 + (r&15)*8 + (k&7)
// -> global_load_lds(1KB) is a contiguous copy; ds_read_b64 at
//    (chunk*512 + lane*8) is exactly the 16x16x32 A/B fragment.
// T also kept row-major fp8 (Tr) for the ctx pass.

#define HDIM 1024
#define NROW 8192
#define TEMP_INV (1.0f / 0.07f)

typedef __attribute__((ext_vector_type(4))) float float4v;  // MFMA C/D
typedef __attribute__((ext_vector_type(2))) float float2v;

// ws layout (bytes)
#define SN_OFF   ((size_t)0)                        // 8 MB fp8 tiled S
#define TN_OFF   ((size_t)8388608)                  // 8 MB fp8 tiled T
#define TR_OFF   ((size_t)16777216)                 // 8 MB fp8 row-major T
#define SUM_OFF  ((size_t)25165824)                 // 8192 float sum-exp
#define PMX_OFF  (SUM_OFF + 32768)                  // 8192 u64 packed (max,~idx)
#define ACC_OFF  (PMX_OFF + 65536)                  // 2 floats
#define CNT_OFF  (ACC_OFF + 64)                     // 1 uint

// async 16B global -> LDS (per-lane gptr; lane i lands at lds_base + i*16)
static __device__ __forceinline__ void gload_lds16(const void* gptr, void* lptr) {
    __builtin_amdgcn_global_load_lds(
        (const __attribute__((address_space(1))) void*)gptr,
        (__attribute__((address_space(3))) void*)(uintptr_t)(uint32_t)(uintptr_t)lptr,
        16, 0, 0);
}

// dot of 4 fp8 pairs packed in two dwords
static __device__ __forceinline__ float fp8dot4(unsigned a, unsigned b) {
    float2v al = __builtin_amdgcn_cvt_pk_f32_fp8((int)a, false);
    float2v ah = __builtin_amdgcn_cvt_pk_f32_fp8((int)a, true);
    float2v bl = __builtin_amdgcn_cvt_pk_f32_fp8((int)b, false);
    float2v bh = __builtin_amdgcn_cvt_pk_f32_fp8((int)b, true);
    return al[0]*bl[0] + al[1]*bl[1] + ah[0]*bh[0] + ah[1]*bh[1];
}

// ---------------- Phase 0: normalize -> fp8, fully coalesced -------------------
__global__ __launch_bounds__(256)
void norm_kernel(const float* __restrict__ hs, const float* __restrict__ ht,
                 char* __restrict__ Sn, char* __restrict__ Tn, char* __restrict__ Tr,
                 float* __restrict__ sumexp, unsigned long long* __restrict__ pmax,
                 float* __restrict__ acc, unsigned* __restrict__ cnt) {
    const int b = blockIdx.x;                       // 0..1023
    const int t = threadIdx.x;
    const int wave = t >> 6, lane = t & 63;
    const bool isT = (b >= 512);
    const int g = isT ? (b - 512) : b;
    const float* in = (isT ? ht : hs) + (size_t)g * 16 * HDIM;
    char* outTiled = (isT ? Tn : Sn) + (size_t)g * 16384;

    __shared__ float sq[16][256];                   // 16 KB, reused as tiled buf
    __shared__ float sscale[16];

    float4v v[16];
    #pragma unroll
    for (int i = 0; i < 16; ++i) {
        v[i] = ((const float4v*)in)[i * 256 + t];
        sq[i][t] = v[i][0]*v[i][0] + v[i][1]*v[i][1] + v[i][2]*v[i][2] + v[i][3]*v[i][3];
    }
    __syncthreads();
    #pragma unroll
    for (int j = 0; j < 4; ++j) {
        const int ri = wave * 4 + j;
        float s = sq[ri][lane] + sq[ri][lane + 64] + sq[ri][lane + 128] + sq[ri][lane + 192];
        #pragma unroll
        for (int off = 1; off < 64; off <<= 1) s += __shfl_xor(s, off);
        if (lane == 0) sscale[ri] = 1.0f / fmaxf(sqrtf(s), 1e-12f);
    }
    __syncthreads();                                // scales ready; sq reads done

    char* tiled = (char*)sq;
    const int koff = (t >> 3) * 512 + ((t >> 1) & 3) * 128 + (t & 1) * 4;  // k0 = 4t
    #pragma unroll
    for (int i = 0; i < 16; ++i) {
        const float sc = sscale[i];
        int d = __builtin_amdgcn_cvt_pk_fp8_f32(v[i][0]*sc, v[i][1]*sc, 0, false);
        d     = __builtin_amdgcn_cvt_pk_fp8_f32(v[i][2]*sc, v[i][3]*sc, d, true);
        *(int*)(tiled + koff + i * 8) = d;
        if (isT) ((int*)(Tr + (size_t)(g * 16 + i) * HDIM))[t] = d;   // coalesced
    }
    __syncthreads();
    #pragma unroll
    for (int j = 0; j < 4; ++j)
        ((uint4*)outTiled)[j * 256 + t] = ((const uint4*)tiled)[j * 256 + t];

    if (!isT && t < 16) { sumexp[b * 16 + t] = 0.f; pmax[b * 16 + t] = 0ull; }
    if (b == 0 && t == 16) { acc[0] = 0.f; acc[1] = 0.f; *cnt = 0u; }
}

// ---------------- Phase 1: BK=128 multi-strip MFMA flash pass ------------------
// Grid 1024 = 32 row-tiles x 32 col-tiles. Block = 512 thr = 8 waves (4x2),
// tile 256 rows x 256 cols as 2 strips of 128, wave tile 64x64.
// K-loop: 8 stages of BK=128 (48 KB: 32 A-chunks + 16 B-chunks, 6 chunks/wave),
// single-buffered (stage -> barrier -> 4 ks x 16 MFMA -> barrier). Halves the
// barrier count vs BK=64 and doubles compute per vmcnt(0) drain; 51 KB LDS
// keeps 3 blocks/CU.
__global__ __launch_bounds__(512, 4)
void flash_kernel(const char* __restrict__ Sn, const char* __restrict__ Tn,
                  float* __restrict__ sumexp, unsigned long long* __restrict__ pmax) {
    __shared__ __align__(16) char As[32768];        // 32 chunks x 1KB (BK=128)
    __shared__ __align__(16) char Bs[16384];        // 16 chunks x 1KB (+pb alias)
    __shared__ float stSe[256];
    __shared__ unsigned long long stPk[256];
    const int t = threadIdx.x;
    const int wave = t >> 6, lane = t & 63;
    const int quad = lane >> 4, l16 = lane & 15;
    const int rbase  = (int)(blockIdx.x & 31) * 256;
    const int cbase0 = (int)(blockIdx.x >> 5) * 256;

    if (t < 256) { stSe[t] = 0.f; stPk[t] = 0ull; }

    const int wm = (wave & 3) * 64, wn = (wave >> 2) * 64;

    // A chunk ca = wave*4+i: rowgroup g=ca>>1, k-half h=ca&1.
    const char* gaB[4];
    #pragma unroll
    for (int i = 0; i < 4; ++i) {
        int ca = wave * 4 + i;
        gaB[i] = Sn + (size_t)(rbase / 16 + (ca >> 1)) * 16384 + (ca & 1) * 1024 + lane * 16;
    }
    // B chunk cb = wave*2+i: colgroup cg=cb>>1, k-half h=cb&1.
    const int cbW[2] = { wave * 2, wave * 2 + 1 };

    for (int s = 0; s < 2; ++s) {
        const int cbase = cbase0 + s * 128;
        const char* gb[2];
        #pragma unroll
        for (int i = 0; i < 2; ++i)
            gb[i] = Tn + (size_t)(cbase / 16 + (cbW[i] >> 1)) * 16384 + (cbW[i] & 1) * 1024 + lane * 16;

        float4v acc[4][4];
        #pragma unroll
        for (int i = 0; i < 4; ++i)
            #pragma unroll
            for (int j = 0; j < 4; ++j) acc[i][j] = (float4v){0.f, 0.f, 0.f, 0.f};

        for (int kb = 0; kb < 8; ++kb) {
            #pragma unroll
            for (int i = 0; i < 4; ++i)
                gload_lds16(gaB[i] + kb * 2048, As + (wave * 4 + i) * 1024);
            #pragma unroll
            for (int i = 0; i < 2; ++i)
                gload_lds16(gb[i] + kb * 2048, Bs + cbW[i] * 1024);
            __syncthreads();                        // loads landed
            #pragma unroll
            for (int ks = 0; ks < 4; ++ks) {
                long af[4], bf[4];
                #pragma unroll
                for (int i = 0; i < 4; ++i)
                    af[i] = *(const long*)(As + (((wave & 3) * 4 + i) * 2 + (ks >> 1)) * 1024
                                              + (ks & 1) * 512 + lane * 8);
                #pragma unroll
                for (int j = 0; j < 4; ++j)
                    bf[j] = *(const long*)(Bs + (((wave >> 2) * 4 + j) * 2 + (ks >> 1)) * 1024
                                              + (ks & 1) * 512 + lane * 8);
                #pragma unroll
                for (int i = 0; i < 4; ++i)
                    #pragma unroll
                    for (int j = 0; j < 4; ++j)
                        acc[i][j] = __builtin_amdgcn_mfma_f32_16x16x32_fp8_fp8(af[i], bf[j], acc[i][j], 0, 0, 0);
            }
            __syncthreads();                        // compute done before overwrite
        }

        // strip epilogue: lane holds sim[rbase+wm+i*16+quad*4+r][cbase+wn+j*16+l16]
        float* pbSe = (float*)Bs;                   // alias (Bs free post-compute)
        unsigned long long* pbPk = (unsigned long long*)(Bs + 1024);
        float se_v[4][4]; unsigned long long pk_v[4][4];
        #pragma unroll
        for (int i = 0; i < 4; ++i) {
            #pragma unroll
            for (int r = 0; r < 4; ++r) {
                float se = 0.f; float mx = -2.f; int mi = 0x7fffffff;
                #pragma unroll
                for (int j = 0; j < 4; ++j) {
                    float v = acc[i][j][r];
                    se += __expf(v * TEMP_INV);
                    int col = cbase + wn + j * 16 + l16;
                    if (v > mx || (v == mx && col < mi)) { mx = v; mi = col; }
                }
                #pragma unroll
                for (int off = 1; off < 16; off <<= 1) {
                    se += __shfl_xor(se, off);
                    float om = __shfl_xor(mx, off);
                    int oi = __shfl_xor(mi, off);
                    if (om > mx || (om == mx && oi < mi)) { mx = om; mi = oi; }
                }
                se_v[i][r] = se;
                pk_v[i][r] = ((unsigned long long)__float_as_uint(mx + 2.0f) << 32)
                             | (unsigned long long)(0xffffffffu - (unsigned)mi);
            }
        }
        if (wave < 4 && l16 == 0) {
            #pragma unroll
            for (int i = 0; i < 4; ++i)
                #pragma unroll
                for (int r = 0; r < 4; ++r) {
                    int rl = wm + i * 16 + quad * 4 + r;
                    pbSe[rl] = se_v[i][r]; pbPk[rl] = pk_v[i][r];
                }
        }
        __syncthreads();
        if (wave >= 4 && l16 == 0) {
            #pragma unroll
            for (int i = 0; i < 4; ++i)
                #pragma unroll
                for (int r = 0; r < 4; ++r) {
                    int rl = wm + i * 16 + quad * 4 + r;
                    float se = se_v[i][r] + pbSe[rl];
                    unsigned long long pk = pk_v[i][r];
                    unsigned long long po = pbPk[rl];
                    if (po > pk) pk = po;
                    stSe[rl] += se;
                    if (pk > stPk[rl]) stPk[rl] = pk;
                }
        }
        __syncthreads();                            // pb reads done before restage
    }

    if (t < 256) {
        atomicAdd(&sumexp[rbase + t], stSe[t]);
        atomicMax(&pmax[rbase + t], stPk[t]);
    }
}

// ---------------- Phase 2: fused loss + ctx + finalize -------------------------
__global__ __launch_bounds__(256)
void tail_kernel(const float* __restrict__ sumexp,
                 const unsigned long long* __restrict__ pmax,
                 const char* __restrict__ Tr,
                 float* __restrict__ acc, unsigned* __restrict__ cnt,
                 float* __restrict__ out) {
    const int blk = blockIdx.x;                     // 0..255
    const int t = threadIdx.x, wave = t >> 6, lane = t & 63;

    if (wave == 0) {
        int r = blk * 32 + (lane & 31);
        unsigned long long p = pmax[r];
        float mx = __uint_as_float((unsigned)(p >> 32)) - 2.0f;
        float loss = logf(sumexp[r]) - mx * TEMP_INV;
        #pragma unroll
        for (int off = 1; off < 32; off <<= 1) loss += __shfl_xor(loss, off);
        if (lane == 0) atomicAdd(acc + 0, loss);    // lanes 0..31 summed once
    }

    float s = 0.f;
    #pragma unroll
    for (int it = 0; it < 8; ++it) {
        int g = blk * 32 + wave * 8 + it;
        if (g < NROW - 1) {
            unsigned long long pa = pmax[g], pb = pmax[g + 1];
            int ia = (int)(0xffffffffu - (unsigned)(pa & 0xffffffffu));
            int ib = (int)(0xffffffffu - (unsigned)(pb & 0xffffffffu));
            uint4 va = ((const uint4*)(Tr + (size_t)ia * HDIM))[lane];
            uint4 vb = ((const uint4*)(Tr + (size_t)ib * HDIM))[lane];
            s += fp8dot4(va.x, vb.x) + fp8dot4(va.y, vb.y)
               + fp8dot4(va.z, vb.z) + fp8dot4(va.w, vb.w);
        }
    }
    #pragma unroll
    for (int off = 1; off < 64; off <<= 1) s += __shfl_xor(s, off);
    __shared__ float red[4];
    if (lane == 0) red[wave] = s;
    __syncthreads();
    if (t == 0) atomicAdd(acc + 1, red[0] + red[1] + red[2] + red[3]);

    __threadfence();
    __shared__ unsigned done;
    if (t == 0) done = atomicAdd(cnt, 1u);
    __syncthreads();
    if (t == 0 && done == 255u) {
        float l0 = atomicAdd(acc + 0, 0.0f);        // device-scope RMW read
        float l1 = atomicAdd(acc + 1, 0.0f);
        out[0] = l0 / (float)NROW;
        out[1] = 1.0f - l1 / (float)(NROW - 1);
    }
}

extern "C" void kernel_launch(void* const* d_in, const int* in_sizes, int n_in,
                              void* d_out, int out_size, void* d_ws, size_t ws_size,
                              hipStream_t stream) {
    const float* hs = (const float*)d_in[0];
    const float* ht = (const float*)d_in[1];
    char* ws = (char*)d_ws;
    char* Sn = ws + SN_OFF;
    char* Tn = ws + TN_OFF;
    char* Tr = ws + TR_OFF;
    float* sumexp = (float*)(ws + SUM_OFF);
    unsigned long long* pmax = (unsigned long long*)(ws + PMX_OFF);
    float* acc = (float*)(ws + ACC_OFF);
    unsigned* cnt = (unsigned*)(ws + CNT_OFF);
    float* out = (float*)d_out;

    norm_kernel<<<1024, 256, 0, stream>>>(hs, ht, Sn, Tn, Tr, sumexp, pmax, acc, cnt);
    flash_kernel<<<1024, 512, 0, stream>>>(Sn, Tn, sumexp, pmax);
    tail_kernel<<<256, 256, 0, stream>>>(sumexp, pmax, Tr, acc, cnt, out);
}